// Round 15
// baseline (209.654 us; speedup 1.0000x reference)
//
#include <hip/hip_runtime.h>
#include <hip/hip_bf16.h>

typedef _Float16 f16;
typedef __attribute__((ext_vector_type(8))) _Float16 f16x8;
typedef __attribute__((ext_vector_type(4))) _Float16 f16x4;
typedef __attribute__((ext_vector_type(4))) float f32x4;

#define MFMA16(a, b, c) __builtin_amdgcn_mfma_f32_16x16x32_f16(a, b, c, 0, 0, 0)
#define GLDS(src, dst) __builtin_amdgcn_global_load_lds( \
    (const __attribute__((address_space(1))) void*)(src), \
    (__attribute__((address_space(3))) void*)(dst), 16, 0, 0)

__device__ inline unsigned pkrtz(float a, float b) {
    __fp16 __attribute__((ext_vector_type(2))) r = __builtin_amdgcn_cvt_pkrtz(a, b);
    unsigned u; __builtin_memcpy(&u, &r, 4);
    return u;
}
__device__ inline void pl32swap(unsigned& a, unsigned& b) {
    asm volatile("v_permlane32_swap_b32 %0, %1" : "+v"(a), "+v"(b));
}
__device__ inline void pl16swap(unsigned& a, unsigned& b) {
    asm volatile("v_permlane16_swap_b32 %0, %1" : "+v"(a), "+v"(b));
}
// raw v_exp_f32 (2^x): skips the OCML exp2f range-check wrapper.
__device__ inline float fexp2(float x) {
#if __has_builtin(__builtin_amdgcn_exp2f)
    return __builtin_amdgcn_exp2f(x);
#else
    return exp2f(x);
#endif
}

// ---------------- fp32 -> fp16 convert: all three inputs in one launch ----------------
__global__ void cvt_all(const float4* __restrict__ x, const float4* __restrict__ qw,
                        const float4* __restrict__ ow,
                        f16x4* __restrict__ xo, f16x4* __restrict__ qwo,
                        f16x4* __restrict__ owo) {
    const int N1 = 2097152, N2 = 786432, N3 = 262144;  // float4 counts
    int i = blockIdx.x * blockDim.x + threadIdx.x;
    int stride = gridDim.x * blockDim.x;
    for (; i < N1 + N2 + N3; i += stride) {
        const float4* src; f16x4* dst; int j;
        if (i < N1)            { src = x;  dst = xo;  j = i; }
        else if (i < N1 + N2)  { src = qw; dst = qwo; j = i - N1; }
        else                   { src = ow; dst = owo; j = i - N1 - N2; }
        float4 f = src[j];
        f16x4 h;
        h.x = (f16)f.x; h.y = (f16)f.y; h.z = (f16)f.z; h.w = (f16)f.w;
        dst[j] = h;
    }
}

// ---------------- GEMM 256x256 (mode 0 / QKV): C = A @ W^T + bias ----------------
// M=8192, N=3072, K=1024. 512 threads (8 waves, 2x4). Per-wave output 128x64
// (8x4 frags) -> LDS reads/MFMA = 0.375 (vs 0.5 at 128^2). BK=64, double-buffered
// (128KB LDS), attn-proven schedule: issue 8 GLDS for tile t+1, vmcnt(8), barrier,
// compute (64 MFMA/wave), lgkmcnt(0), barrier. Chunk-XOR swizzle: conflict-free.
// Epilogue scatters Q (scaled 0.125*log2e) / K [bh][s][d], V^T [bh][d][s].
__global__ __launch_bounds__(512, 1) void gemm256_qkv(
    const f16* __restrict__ A, const f16* __restrict__ Bw,
    const float* __restrict__ bias,
    f16* __restrict__ qo, f16* __restrict__ ko, f16* __restrict__ vo)
{
    __shared__ __align__(16) f16 As[2][256 * 64];
    __shared__ __align__(16) f16 Bs[2][256 * 64];
    const int tid = threadIdx.x;
    const int wave = tid >> 6, lane = tid & 63;
    const int wr = wave >> 2, wc = wave & 3;          // 2 x 4 wave grid
    const int brow = blockIdx.y * 256;
    const int bcol = blockIdx.x * 256;
    const int K = 1024;
    const f16* Ab = A + (size_t)brow * K;
    const f16* Bb = Bw + (size_t)bcol * K;

    const int cl = lane & 15, rg = lane >> 4;
    const int swz = cl & 7;
    // staging geometry: chunk id = q*512 + tid (q=0..3); row = id>>3; c = tid&7
    const int schunk = tid & 7;

    const f32x4 fz = {0.0f, 0.0f, 0.0f, 0.0f};
    f32x4 acc[8][4];
#pragma unroll
    for (int m = 0; m < 8; ++m)
#pragma unroll
        for (int n = 0; n < 4; ++n) acc[m][n] = fz;

    // stage one K-tile (k0) into buf b: 4 GLDS for A + 4 for B per thread
#define STAGE(b, k0)                                                             \
    {                                                                            \
        _Pragma("unroll")                                                        \
        for (int q = 0; q < 4; ++q) {                                            \
            int id = q * 512 + tid;                                              \
            int row = id >> 3;                                                   \
            int sc = (schunk ^ (row & 7)) * 8;                                   \
            GLDS(Ab + (size_t)row * 1024 + (k0) + sc, &As[b][id * 8 - lane * 8 + lane * 8]); \
        }                                                                        \
        _Pragma("unroll")                                                        \
        for (int q = 0; q < 4; ++q) {                                            \
            int id = q * 512 + tid;                                              \
            int row = id >> 3;                                                   \
            int sc = (schunk ^ (row & 7)) * 8;                                   \
            GLDS(Bb + (size_t)row * 1024 + (k0) + sc, &Bs[b][id * 8]);           \
        }                                                                        \
    }

    STAGE(0, 0);   // prologue: tile 0 -> buf 0

    int cur = 0;
    for (int t = 0; t < 16; ++t) {
        if (t < 15) {
            STAGE(cur ^ 1, (t + 1) * 64);
            asm volatile("s_waitcnt vmcnt(8)" ::: "memory");
        } else {
            asm volatile("s_waitcnt vmcnt(0)" ::: "memory");
        }
        __builtin_amdgcn_sched_barrier(0);
        __builtin_amdgcn_s_barrier();
        __builtin_amdgcn_sched_barrier(0);

        __builtin_amdgcn_s_setprio(1);
#pragma unroll
        for (int kk = 0; kk < 2; ++kk) {
            f16x8 af[8];
#pragma unroll
            for (int m = 0; m < 8; ++m)
                af[m] = *(const f16x8*)(
                    &As[cur][((wr * 128 + m * 16 + cl) * 8 + (((kk << 2) | rg) ^ swz)) * 8]);
#pragma unroll
            for (int n = 0; n < 4; ++n) {
                f16x8 bf = *(const f16x8*)(
                    &Bs[cur][((wc * 64 + n * 16 + cl) * 8 + (((kk << 2) | rg) ^ swz)) * 8]);
#pragma unroll
                for (int m = 0; m < 8; ++m)
                    acc[m][n] = MFMA16(af[m], bf, acc[m][n]);
            }
        }
        __builtin_amdgcn_s_setprio(0);

        asm volatile("s_waitcnt lgkmcnt(0)" ::: "memory");
        __builtin_amdgcn_sched_barrier(0);
        __builtin_amdgcn_s_barrier();
        __builtin_amdgcn_sched_barrier(0);
        cur ^= 1;
    }
#undef STAGE

    // epilogue: C/D layout col = lane&15, row = (lane>>4)*4 + r
#pragma unroll
    for (int n = 0; n < 4; ++n) {
        int col = bcol + wc * 64 + n * 16 + cl;       // 0..3071
        float bs = bias[col];
        int which = col >> 10;
        int h = (col & 1023) >> 6;
        int d = col & 63;
        if (which == 2) {
            // V transposed: vo[bh][d][s]
#pragma unroll
            for (int m = 0; m < 8; ++m) {
                int row0 = brow + wr * 128 + m * 16 + rg * 4;
                int bb = row0 >> 11, s0 = row0 & 2047;
                f16x4 pk;
#pragma unroll
                for (int r = 0; r < 4; ++r) pk[r] = (f16)(acc[m][n][r] + bs);
                *(f16x4*)(vo + ((size_t)(bb * 16 + h) * 64 + d) * 2048 + s0) = pk;
            }
        } else {
            f16* dst = (which == 0) ? qo : ko;
            float scale = (which == 0) ? 0.125f * 1.44269504f : 1.0f;
#pragma unroll
            for (int m = 0; m < 8; ++m) {
#pragma unroll
                for (int r = 0; r < 4; ++r) {
                    int row = brow + wr * 128 + m * 16 + rg * 4 + r;
                    int bb = row >> 11, s = row & 2047;
                    dst[((size_t)(bb * 16 + h) * 2048 + s) * 64 + d] =
                        (f16)((acc[m][n][r] + bs) * scale);
                }
            }
        }
    }
}

// ---------------- GEMM 128x128 (mode 1 / out-proj): C = A @ W^T + bias, fp32 out ----------------
__global__ __launch_bounds__(256, 2) void gemm_out(
    const f16* __restrict__ A, const f16* __restrict__ Bw,
    const float* __restrict__ bias, float* __restrict__ outp)
{
    __shared__ __align__(16) f16 As[128 * 64];
    __shared__ __align__(16) f16 Bs[128 * 64];
    const int tid = threadIdx.x;
    const int wave = tid >> 6, lane = tid & 63;
    const int wr = wave >> 1, wc = wave & 1;
    const int brow = blockIdx.y * 128;
    const int bcol = blockIdx.x * 128;
    const int K = 1024;
    const f16* Ab = A + (size_t)brow * K;
    const f16* Bb = Bw + (size_t)bcol * K;

    const f32x4 fz = {0.0f, 0.0f, 0.0f, 0.0f};
    f32x4 acc[4][4];
#pragma unroll
    for (int m = 0; m < 4; ++m)
#pragma unroll
        for (int n = 0; n < 4; ++n) acc[m][n] = fz;

    const int lrow = lane >> 3;
    const int lcol = (lane & 7) * 8;
    const int cl = lane & 15, rg = lane >> 4;

    for (int k0 = 0; k0 < K; k0 += 64) {
        __syncthreads();
#pragma unroll
        for (int c = 0; c < 4; ++c) {
            const int ch = wave * 4 + c;
            GLDS(Ab + (size_t)(ch * 8 + lrow) * K + k0 + lcol, As + ch * 512);
            GLDS(Bb + (size_t)(ch * 8 + lrow) * K + k0 + lcol, Bs + ch * 512);
        }
        __syncthreads();
#pragma unroll
        for (int kk = 0; kk < 2; ++kk) {
            f16x8 af[4], bfr[4];
#pragma unroll
            for (int m = 0; m < 4; ++m)
                af[m] = *(const f16x8*)(As + (wr * 64 + m * 16 + cl) * 64 + kk * 32 + rg * 8);
#pragma unroll
            for (int n = 0; n < 4; ++n)
                bfr[n] = *(const f16x8*)(Bs + (wc * 64 + n * 16 + cl) * 64 + kk * 32 + rg * 8);
#pragma unroll
            for (int m = 0; m < 4; ++m)
#pragma unroll
                for (int n = 0; n < 4; ++n)
                    acc[m][n] = MFMA16(af[m], bfr[n], acc[m][n]);
        }
    }
#pragma unroll
    for (int n = 0; n < 4; ++n) {
        int col = bcol + wc * 64 + n * 16 + cl;
        float bs = bias[col];
#pragma unroll
        for (int m = 0; m < 4; ++m)
#pragma unroll
            for (int r = 0; r < 4; ++r) {
                int row = brow + wr * 64 + m * 16 + rg * 4 + r;
                outp[(size_t)row * 1024 + col] = acc[m][n][r] + bs;
            }
    }
}

// ---------------- flash attention (r13 v9, proven 84us) ----------------
__global__ __launch_bounds__(256, 3) void attn_fwd(
    const f16* __restrict__ Q, const f16* __restrict__ Kg,
    const f16* __restrict__ Vtg, f16* __restrict__ Op, float* __restrict__ lp)
{
    const int bid = blockIdx.x;                       // 0..2047
    const int vid = (bid & 7) * 256 + (bid >> 3);     // XCD-chunked remap (bijective)
    const int qx = vid & 15;
    const int bh = (vid >> 4) & 63;
    const int z  = vid >> 10;
    const int q0 = qx * 128;
    const int kb = z * 1024;
    const int tid = threadIdx.x;
    const int wave = tid >> 6, lane = tid & 63;
    const int cl = lane & 15, rg = lane >> 4;
    const f16* Qh = Q + (size_t)bh * 2048 * 64;
    const f16* Kp = Kg + (size_t)bh * 2048 * 64 + (size_t)kb * 64;
    const f16* Vp = Vtg + (size_t)bh * 64 * 2048 + kb;

    __shared__ __align__(16) f16 Ks[2][64 * 64];
    __shared__ __align__(16) f16 Vs[2][64 * 64];

    f16x8 aq[2][2];
#pragma unroll
    for (int m = 0; m < 2; ++m) {
        const f16* qptr = Qh + (size_t)(q0 + wave * 32 + m * 16 + cl) * 64 + rg * 8;
        aq[m][0] = *(const f16x8*)(qptr);
        aq[m][1] = *(const f16x8*)(qptr + 32);
    }

    f16x8 ones8;
#pragma unroll
    for (int j = 0; j < 8; ++j) ones8[j] = (f16)1.0f;

    const int srow0 = tid >> 3;
    const int schunk = tid & 7;
    const int swz = cl & 7;

    const f32x4 fz = {0.0f, 0.0f, 0.0f, 0.0f};
    f32x4 oacc[2][4];
    f32x4 loacc[2];
#pragma unroll
    for (int m = 0; m < 2; ++m) {
        loacc[m] = fz;
#pragma unroll
        for (int da = 0; da < 4; ++da) oacc[m][da] = fz;
    }

#pragma unroll
    for (int c = 0; c < 2; ++c) {
        int row = c * 32 + srow0;
        int sc = (schunk ^ (row & 7)) * 8;
        GLDS(Kp + (size_t)row * 64 + sc,   &Ks[0][(c * 256 + wave * 64) * 8]);
        GLDS(Vp + (size_t)row * 2048 + sc, &Vs[0][(c * 256 + wave * 64) * 8]);
    }

    int cur = 0;
    for (int t = 0; t < 16; ++t) {
        if (t < 15) {
            const int kt = (t + 1) * 64;
#pragma unroll
            for (int c = 0; c < 2; ++c) {
                int row = c * 32 + srow0;
                int sc = (schunk ^ (row & 7)) * 8;
                GLDS(Kp + (size_t)(kt + row) * 64 + sc, &Ks[cur ^ 1][(c * 256 + wave * 64) * 8]);
                GLDS(Vp + (size_t)row * 2048 + kt + sc, &Vs[cur ^ 1][(c * 256 + wave * 64) * 8]);
            }
            asm volatile("s_waitcnt vmcnt(4)" ::: "memory");
        } else {
            asm volatile("s_waitcnt vmcnt(0)" ::: "memory");
        }
        __builtin_amdgcn_sched_barrier(0);
        __builtin_amdgcn_s_barrier();
        __builtin_amdgcn_sched_barrier(0);

        f32x4 sacc[2][4];
        __builtin_amdgcn_s_setprio(1);
#pragma unroll
        for (int fn = 0; fn < 4; ++fn) {
            f16x8 ak0 = *(const f16x8*)(
                &Ks[cur][(fn * 16 + cl) * 64 + (rg ^ swz) * 8]);
            f16x8 ak1 = *(const f16x8*)(
                &Ks[cur][(fn * 16 + cl) * 64 + ((4 | rg) ^ swz) * 8]);
            sacc[0][fn] = MFMA16(ak0, aq[0][0], fz);
            sacc[0][fn] = MFMA16(ak1, aq[0][1], sacc[0][fn]);
            sacc[1][fn] = MFMA16(ak0, aq[1][0], fz);
            sacc[1][fn] = MFMA16(ak1, aq[1][1], sacc[1][fn]);
        }
        __builtin_amdgcn_s_setprio(0);

        f16x8 pbv[2][2];
#pragma unroll
        for (int m = 0; m < 2; ++m) {
            unsigned X0[4], X1[4];
#pragma unroll
            for (int fn = 0; fn < 4; ++fn) {
                float p0 = fexp2(sacc[m][fn][0]);
                float p1 = fexp2(sacc[m][fn][1]);
                float p2 = fexp2(sacc[m][fn][2]);
                float p3 = fexp2(sacc[m][fn][3]);
                X0[fn] = pkrtz(p0, p1);
                X1[fn] = pkrtz(p2, p3);
            }
#pragma unroll
            for (int kk = 0; kk < 2; ++kk) {
                unsigned a0 = X0[2 * kk], b0 = X0[2 * kk + 1];
                unsigned a1 = X1[2 * kk], b1 = X1[2 * kk + 1];
                pl32swap(a0, b0); pl16swap(a0, b0);
                pl32swap(a1, b1); pl16swap(a1, b1);
                unsigned fr[4] = {a0, a1, b0, b1};
                __builtin_memcpy(&pbv[m][kk], fr, 16);
            }
        }

        __builtin_amdgcn_s_setprio(1);
#pragma unroll
        for (int kk = 0; kk < 2; ++kk) {
            loacc[0] = MFMA16(ones8, pbv[0][kk], loacc[0]);
            loacc[1] = MFMA16(ones8, pbv[1][kk], loacc[1]);
#pragma unroll
            for (int da = 0; da < 4; ++da) {
                f16x8 av = *(const f16x8*)(
                    &Vs[cur][(da * 16 + cl) * 64 + (((kk << 2) | rg) ^ swz) * 8]);
                oacc[0][da] = MFMA16(av, pbv[0][kk], oacc[0][da]);
                oacc[1][da] = MFMA16(av, pbv[1][kk], oacc[1][da]);
            }
        }
        __builtin_amdgcn_s_setprio(0);

        asm volatile("s_waitcnt lgkmcnt(0)" ::: "memory");
        __builtin_amdgcn_sched_barrier(0);
        __builtin_amdgcn_s_barrier();
        __builtin_amdgcn_sched_barrier(0);
        cur ^= 1;
    }

    const int bb = bh >> 4, h = bh & 15;
#pragma unroll
    for (int m = 0; m < 2; ++m) {
        int s = q0 + wave * 32 + m * 16 + cl;
        int row = (bb * 2048 + s) * 16 + h;
        f16* op = Op + (size_t)z * 8388608 + (size_t)row * 64;
#pragma unroll
        for (int da = 0; da < 4; ++da) {
            f16x4 ov;
#pragma unroll
            for (int r = 0; r < 4; ++r) ov[r] = (f16)oacc[m][da][r];
            *(f16x4*)(op + da * 16 + rg * 4) = ov;
        }
        if (rg == 0) lp[z * 131072 + row] = loacc[m][0];
    }
}

// ---------------- merge: AO = (O0 + O1) / (l0 + l1) ----------------
__global__ __launch_bounds__(256) void attn_merge(
    const f16* __restrict__ Op, const float* __restrict__ lp, f16* __restrict__ AO)
{
    int i = blockIdx.x * 256 + threadIdx.x;
    int row = i >> 3, c = (i & 7) * 8;
    float inv = 1.0f / (lp[row] + lp[row + 131072]);
    f16x8 a = *(const f16x8*)(Op + (size_t)row * 64 + c);
    f16x8 b = *(const f16x8*)(Op + 8388608 + (size_t)row * 64 + c);
    f16x8 o;
#pragma unroll
    for (int j = 0; j < 8; ++j) o[j] = (f16)(((float)a[j] + (float)b[j]) * inv);
    *(f16x8*)(AO + (size_t)row * 64 + c) = o;
}

extern "C" void kernel_launch(void* const* d_in, const int* in_sizes, int n_in,
                              void* d_out, int out_size, void* d_ws, size_t ws_size,
                              hipStream_t stream) {
    const float* x     = (const float*)d_in[0];
    const float* qkv_w = (const float*)d_in[1];
    const float* qkv_b = (const float*)d_in[2];
    const float* out_w = (const float*)d_in[3];
    const float* out_b = (const float*)d_in[4];
    float* out = (float*)d_out;

    char* ws = (char*)d_ws;
    size_t off = 0;
    f16* x_h  = (f16*)(ws + off); off += 16777216;   // 8192x1024 fp16
    f16* qw_h = (f16*)(ws + off); off += 6291456;    // 3072x1024
    f16* ow_h = (f16*)(ws + off); off += 2097152;    // 1024x1024
    f16* Qb   = (f16*)(ws + off); off += 16777216;   // [bh][s][d] (scaled)
    f16* Kb   = (f16*)(ws + off); off += 16777216;   // [bh][s][d]
    f16* Vb   = (f16*)(ws + off); off += 16777216;   // [bh][d][s] (transposed)
    f16* AO   = (f16*)(ws + off); off += 16777216;   // attn out [b,s,h,d]
    f16* Opart= (f16*)(ws + off); off += 33554432;   // 2 x unnormalized O partials
    float* lpart = (float*)(ws + off); off += 1048576;  // 2 x 131072 l partials

    cvt_all<<<2048, 256, 0, stream>>>((const float4*)x, (const float4*)qkv_w,
                                      (const float4*)out_w,
                                      (f16x4*)x_h, (f16x4*)qw_h, (f16x4*)ow_h);

    dim3 g1(12, 32);   // N=3072/256, M=8192/256
    gemm256_qkv<<<g1, dim3(512), 0, stream>>>(x_h, qw_h, qkv_b, Qb, Kb, Vb);
    attn_fwd<<<2048, dim3(256), 0, stream>>>(Qb, Kb, Vb, Opart, lpart);
    attn_merge<<<4096, dim3(256), 0, stream>>>(Opart, lpart, AO);
    dim3 g2(8, 64);    // N=1024/128, M=8192/128
    gemm_out<<<g2, dim3(256), 0, stream>>>(AO, ow_h, out_b, out);
}

// Round 16
// 189.177 us; speedup vs baseline: 1.1082x; 1.1082x over previous
//
#include <hip/hip_runtime.h>
#include <hip/hip_bf16.h>

typedef _Float16 f16;
typedef __attribute__((ext_vector_type(8))) _Float16 f16x8;
typedef __attribute__((ext_vector_type(4))) _Float16 f16x4;
typedef __attribute__((ext_vector_type(4))) float f32x4;

#define MFMA16(a, b, c) __builtin_amdgcn_mfma_f32_16x16x32_f16(a, b, c, 0, 0, 0)
#define GLDS(src, dst) __builtin_amdgcn_global_load_lds( \
    (const __attribute__((address_space(1))) void*)(src), \
    (__attribute__((address_space(3))) void*)(dst), 16, 0, 0)

__device__ inline unsigned pkrtz(float a, float b) {
    __fp16 __attribute__((ext_vector_type(2))) r = __builtin_amdgcn_cvt_pkrtz(a, b);
    unsigned u; __builtin_memcpy(&u, &r, 4);
    return u;
}
__device__ inline void pl32swap(unsigned& a, unsigned& b) {
    asm volatile("v_permlane32_swap_b32 %0, %1" : "+v"(a), "+v"(b));
}
__device__ inline void pl16swap(unsigned& a, unsigned& b) {
    asm volatile("v_permlane16_swap_b32 %0, %1" : "+v"(a), "+v"(b));
}
// raw v_exp_f32 (2^x): skips the OCML exp2f range-check wrapper.
__device__ inline float fexp2(float x) {
#if __has_builtin(__builtin_amdgcn_exp2f)
    return __builtin_amdgcn_exp2f(x);
#else
    return exp2f(x);
#endif
}

// ---------------- fp32 -> fp16 convert: all three inputs in one launch ----------------
__global__ void cvt_all(const float4* __restrict__ x, const float4* __restrict__ qw,
                        const float4* __restrict__ ow,
                        f16x4* __restrict__ xo, f16x4* __restrict__ qwo,
                        f16x4* __restrict__ owo) {
    const int N1 = 2097152, N2 = 786432, N3 = 262144;  // float4 counts
    int i = blockIdx.x * blockDim.x + threadIdx.x;
    int stride = gridDim.x * blockDim.x;
    for (; i < N1 + N2 + N3; i += stride) {
        const float4* src; f16x4* dst; int j;
        if (i < N1)            { src = x;  dst = xo;  j = i; }
        else if (i < N1 + N2)  { src = qw; dst = qwo; j = i - N1; }
        else                   { src = ow; dst = owo; j = i - N1 - N2; }
        float4 f = src[j];
        f16x4 h;
        h.x = (f16)f.x; h.y = (f16)f.y; h.z = (f16)f.z; h.w = (f16)f.w;
        dst[j] = h;
    }
}

// ---------------- GEMM: C[M,N] = A[M,K] @ W[N,K]^T + bias ----------------
// Flat grid, XCD-chunked remap (each XCD keeps its A-panels L2-private).
// mode 0: N=3072 -> Q [bh][s][d] scaled 0.125*log2(e), K [bh][s][d], V^T [bh][d][s].
// mode 1: N=1024, fp32 out.
__global__ __launch_bounds__(256, 2) void gemm_bt(
    const f16* __restrict__ A, const f16* __restrict__ Bw,
    const float* __restrict__ bias, int mode, int nbn, int chunk,
    f16* __restrict__ qo, f16* __restrict__ ko, f16* __restrict__ vo,
    float* __restrict__ outp)
{
    __shared__ __align__(16) f16 As[128 * 64];
    __shared__ __align__(16) f16 Bs[128 * 64];
    const int bid = blockIdx.x;
    const int vid = (bid & 7) * chunk + (bid >> 3);   // bijective: grid = 8*chunk
    const int brow = (vid / nbn) * 128;
    const int bcol = (vid % nbn) * 128;
    const int tid = threadIdx.x;
    const int wave = tid >> 6, lane = tid & 63;
    const int wr = wave >> 1, wc = wave & 1;
    const int K = 1024;
    const f16* Ab = A + (size_t)brow * K;
    const f16* Bb = Bw + (size_t)bcol * K;

    const f32x4 fz = {0.0f, 0.0f, 0.0f, 0.0f};
    f32x4 acc[4][4];
#pragma unroll
    for (int m = 0; m < 4; ++m)
#pragma unroll
        for (int n = 0; n < 4; ++n) acc[m][n] = fz;

    const int lrow = lane >> 3;
    const int lcol = (lane & 7) * 8;
    const int cl = lane & 15, rg = lane >> 4;

    for (int k0 = 0; k0 < K; k0 += 64) {
        __syncthreads();
#pragma unroll
        for (int c = 0; c < 4; ++c) {
            const int ch = wave * 4 + c;
            GLDS(Ab + (size_t)(ch * 8 + lrow) * K + k0 + lcol, As + ch * 512);
            GLDS(Bb + (size_t)(ch * 8 + lrow) * K + k0 + lcol, Bs + ch * 512);
        }
        __syncthreads();
#pragma unroll
        for (int kk = 0; kk < 2; ++kk) {
            f16x8 af[4], bfr[4];
#pragma unroll
            for (int m = 0; m < 4; ++m)
                af[m] = *(const f16x8*)(As + (wr * 64 + m * 16 + cl) * 64 + kk * 32 + rg * 8);
#pragma unroll
            for (int n = 0; n < 4; ++n)
                bfr[n] = *(const f16x8*)(Bs + (wc * 64 + n * 16 + cl) * 64 + kk * 32 + rg * 8);
#pragma unroll
            for (int m = 0; m < 4; ++m)
#pragma unroll
                for (int n = 0; n < 4; ++n)
                    acc[m][n] = MFMA16(af[m], bfr[n], acc[m][n]);
        }
    }

    // C/D layout: col = lane&15, row = (lane>>4)*4 + r
    if (mode == 0) {
#pragma unroll
        for (int n = 0; n < 4; ++n) {
            int col = bcol + wc * 64 + n * 16 + cl;
            float bs = bias[col];
            int which = col >> 10;
            int h = (col & 1023) >> 6;
            int d = col & 63;
            if (which == 2) {
                // V transposed: vo[bh][d][s]
#pragma unroll
                for (int m = 0; m < 4; ++m) {
                    int row0 = brow + wr * 64 + m * 16 + rg * 4;
                    int bb = row0 >> 11, s0 = row0 & 2047;
                    f16x4 pk;
#pragma unroll
                    for (int r = 0; r < 4; ++r) pk[r] = (f16)(acc[m][n][r] + bs);
                    *(f16x4*)(vo + ((size_t)(bb * 16 + h) * 64 + d) * 2048 + s0) = pk;
                }
            } else {
                f16* dst = (which == 0) ? qo : ko;
                // Q: fold 1/sqrt(64) AND log2(e) (softmax runs in exp2 domain)
                float scale = (which == 0) ? 0.125f * 1.44269504f : 1.0f;
#pragma unroll
                for (int m = 0; m < 4; ++m) {
#pragma unroll
                    for (int r = 0; r < 4; ++r) {
                        int row = brow + wr * 64 + m * 16 + rg * 4 + r;
                        int bb = row >> 11, s = row & 2047;
                        dst[((size_t)(bb * 16 + h) * 2048 + s) * 64 + d] =
                            (f16)((acc[m][n][r] + bs) * scale);
                    }
                }
            }
        }
    } else {
#pragma unroll
        for (int n = 0; n < 4; ++n) {
            int col = bcol + wc * 64 + n * 16 + cl;
            float bs = bias[col];
#pragma unroll
            for (int m = 0; m < 4; ++m)
#pragma unroll
                for (int r = 0; r < 4; ++r) {
                    int row = brow + wr * 64 + m * 16 + rg * 4 + r;
                    outp[(size_t)row * 1024 + col] = acc[m][n][r] + bs;
                }
        }
    }
}

// ---------------- flash attention v11: r13 structure, NO split-K (merge eliminated) ----------------
// Flat grid 1024, XCD-remapped: all 16 q-blocks of one bh land on ONE XCD (K/V
// L2-local). 4 waves; wave owns 32 q-rows; lane owns q = wave*32+m*16+cl.
// Full 2048-key sweep (32 tiles), no-max exp2 softmax (raw v_exp_f32), dbuf 32KB,
// l via all-ones MFMA, in-register P relayout (permlane). Epilogue normalizes
// in-register (1/l) and writes AO directly — no partials, no merge pass.
__global__ __launch_bounds__(256, 3) void attn_fwd(
    const f16* __restrict__ Q, const f16* __restrict__ Kg,
    const f16* __restrict__ Vtg, f16* __restrict__ AO)
{
    const int bid = blockIdx.x;                       // 0..1023
    const int vid = (bid & 7) * 128 + (bid >> 3);     // XCD-chunked remap (bijective)
    const int qx = vid & 15;
    const int bh = vid >> 4;                          // 0..63
    const int q0 = qx * 128;
    const int tid = threadIdx.x;
    const int wave = tid >> 6, lane = tid & 63;
    const int cl = lane & 15, rg = lane >> 4;
    const f16* Qh = Q + (size_t)bh * 2048 * 64;
    const f16* Kp = Kg + (size_t)bh * 2048 * 64;      // [s][d]
    const f16* Vp = Vtg + (size_t)bh * 64 * 2048;     // [d][s]

    __shared__ __align__(16) f16 Ks[2][64 * 64];
    __shared__ __align__(16) f16 Vs[2][64 * 64];

    f16x8 aq[2][2];
#pragma unroll
    for (int m = 0; m < 2; ++m) {
        const f16* qptr = Qh + (size_t)(q0 + wave * 32 + m * 16 + cl) * 64 + rg * 8;
        aq[m][0] = *(const f16x8*)(qptr);
        aq[m][1] = *(const f16x8*)(qptr + 32);
    }

    f16x8 ones8;
#pragma unroll
    for (int j = 0; j < 8; ++j) ones8[j] = (f16)1.0f;

    const int srow0 = tid >> 3;
    const int schunk = tid & 7;
    const int swz = cl & 7;

    const f32x4 fz = {0.0f, 0.0f, 0.0f, 0.0f};
    f32x4 oacc[2][4];
    f32x4 loacc[2];
#pragma unroll
    for (int m = 0; m < 2; ++m) {
        loacc[m] = fz;
#pragma unroll
        for (int da = 0; da < 4; ++da) oacc[m][da] = fz;
    }

#pragma unroll
    for (int c = 0; c < 2; ++c) {
        int row = c * 32 + srow0;
        int sc = (schunk ^ (row & 7)) * 8;
        GLDS(Kp + (size_t)row * 64 + sc,   &Ks[0][(c * 256 + wave * 64) * 8]);
        GLDS(Vp + (size_t)row * 2048 + sc, &Vs[0][(c * 256 + wave * 64) * 8]);
    }

    int cur = 0;
    for (int t = 0; t < 32; ++t) {
        if (t < 31) {
            const int kt = (t + 1) * 64;
#pragma unroll
            for (int c = 0; c < 2; ++c) {
                int row = c * 32 + srow0;
                int sc = (schunk ^ (row & 7)) * 8;
                GLDS(Kp + (size_t)(kt + row) * 64 + sc, &Ks[cur ^ 1][(c * 256 + wave * 64) * 8]);
                GLDS(Vp + (size_t)row * 2048 + kt + sc, &Vs[cur ^ 1][(c * 256 + wave * 64) * 8]);
            }
            asm volatile("s_waitcnt vmcnt(4)" ::: "memory");
        } else {
            asm volatile("s_waitcnt vmcnt(0)" ::: "memory");
        }
        __builtin_amdgcn_sched_barrier(0);
        __builtin_amdgcn_s_barrier();
        __builtin_amdgcn_sched_barrier(0);

        // ---- S^T = K Q^T ----
        f32x4 sacc[2][4];
        __builtin_amdgcn_s_setprio(1);
#pragma unroll
        for (int fn = 0; fn < 4; ++fn) {
            f16x8 ak0 = *(const f16x8*)(
                &Ks[cur][(fn * 16 + cl) * 64 + (rg ^ swz) * 8]);
            f16x8 ak1 = *(const f16x8*)(
                &Ks[cur][(fn * 16 + cl) * 64 + ((4 | rg) ^ swz) * 8]);
            sacc[0][fn] = MFMA16(ak0, aq[0][0], fz);
            sacc[0][fn] = MFMA16(ak1, aq[0][1], sacc[0][fn]);
            sacc[1][fn] = MFMA16(ak0, aq[1][0], fz);
            sacc[1][fn] = MFMA16(ak1, aq[1][1], sacc[1][fn]);
        }
        __builtin_amdgcn_s_setprio(0);

        // ---- no-max softmax: P = exp2(S); pack + permlane relayout ----
        f16x8 pbv[2][2];
#pragma unroll
        for (int m = 0; m < 2; ++m) {
            unsigned X0[4], X1[4];
#pragma unroll
            for (int fn = 0; fn < 4; ++fn) {
                float p0 = fexp2(sacc[m][fn][0]);
                float p1 = fexp2(sacc[m][fn][1]);
                float p2 = fexp2(sacc[m][fn][2]);
                float p3 = fexp2(sacc[m][fn][3]);
                X0[fn] = pkrtz(p0, p1);
                X1[fn] = pkrtz(p2, p3);
            }
#pragma unroll
            for (int kk = 0; kk < 2; ++kk) {
                unsigned a0 = X0[2 * kk], b0 = X0[2 * kk + 1];
                unsigned a1 = X1[2 * kk], b1 = X1[2 * kk + 1];
                pl32swap(a0, b0); pl16swap(a0, b0);
                pl32swap(a1, b1); pl16swap(a1, b1);
                unsigned fr[4] = {a0, a1, b0, b1};
                __builtin_memcpy(&pbv[m][kk], fr, 16);
            }
        }

        // ---- O^T += V^T P^T ; l += ones @ P ----
        __builtin_amdgcn_s_setprio(1);
#pragma unroll
        for (int kk = 0; kk < 2; ++kk) {
            loacc[0] = MFMA16(ones8, pbv[0][kk], loacc[0]);
            loacc[1] = MFMA16(ones8, pbv[1][kk], loacc[1]);
#pragma unroll
            for (int da = 0; da < 4; ++da) {
                f16x8 av = *(const f16x8*)(
                    &Vs[cur][(da * 16 + cl) * 64 + (((kk << 2) | rg) ^ swz) * 8]);
                oacc[0][da] = MFMA16(av, pbv[0][kk], oacc[0][da]);
                oacc[1][da] = MFMA16(av, pbv[1][kk], oacc[1][da]);
            }
        }
        __builtin_amdgcn_s_setprio(0);

        asm volatile("s_waitcnt lgkmcnt(0)" ::: "memory");
        __builtin_amdgcn_sched_barrier(0);
        __builtin_amdgcn_s_barrier();
        __builtin_amdgcn_sched_barrier(0);
        cur ^= 1;
    }

    // epilogue: normalize in-register, write AO[b, s, h, d] directly
    const int bb = bh >> 4, h = bh & 15;
#pragma unroll
    for (int m = 0; m < 2; ++m) {
        float inv = 1.0f / loacc[m][0];
        int s = q0 + wave * 32 + m * 16 + cl;
        f16* op = AO + ((size_t)(bb * 2048 + s) * 16 + h) * 64;
#pragma unroll
        for (int da = 0; da < 4; ++da) {
            f16x4 ov;
#pragma unroll
            for (int r = 0; r < 4; ++r) ov[r] = (f16)(oacc[m][da][r] * inv);
            *(f16x4*)(op + da * 16 + rg * 4) = ov;
        }
    }
}

extern "C" void kernel_launch(void* const* d_in, const int* in_sizes, int n_in,
                              void* d_out, int out_size, void* d_ws, size_t ws_size,
                              hipStream_t stream) {
    const float* x     = (const float*)d_in[0];
    const float* qkv_w = (const float*)d_in[1];
    const float* qkv_b = (const float*)d_in[2];
    const float* out_w = (const float*)d_in[3];
    const float* out_b = (const float*)d_in[4];
    float* out = (float*)d_out;

    char* ws = (char*)d_ws;
    size_t off = 0;
    f16* x_h  = (f16*)(ws + off); off += 16777216;   // 8192x1024 fp16
    f16* qw_h = (f16*)(ws + off); off += 6291456;    // 3072x1024
    f16* ow_h = (f16*)(ws + off); off += 2097152;    // 1024x1024
    f16* Qb   = (f16*)(ws + off); off += 16777216;   // [bh][s][d] (scaled)
    f16* Kb   = (f16*)(ws + off); off += 16777216;   // [bh][s][d]
    f16* Vb   = (f16*)(ws + off); off += 16777216;   // [bh][d][s] (transposed)
    f16* AO   = (f16*)(ws + off); off += 16777216;   // attn out [b,s,h,d]

    cvt_all<<<2048, 256, 0, stream>>>((const float4*)x, (const float4*)qkv_w,
                                      (const float4*)out_w,
                                      (f16x4*)x_h, (f16x4*)qw_h, (f16x4*)ow_h);

    // GEMM1: 1536 blocks (24 n x 64 m), XCD chunk = 192
    gemm_bt<<<1536, dim3(256), 0, stream>>>(x_h, qw_h, qkv_b, 0, 24, 192,
                                            Qb, Kb, Vb, nullptr);
    attn_fwd<<<1024, dim3(256), 0, stream>>>(Qb, Kb, Vb, AO);
    // GEMM2: 512 blocks (8 n x 64 m), XCD chunk = 64
    gemm_bt<<<512, dim3(256), 0, stream>>>(AO, ow_h, out_b, 1, 8, 64,
                                           nullptr, nullptr, nullptr, out);
}